// Round 7
// baseline (1505.768 us; speedup 1.0000x reference)
//
#include <hip/hip_runtime.h>

#define BB 32
#define TT 2048
#define DD 256
#define HH 256
#define AA 128
#define CC 4367
#define NSTEPS 22

typedef unsigned short ushortT;
typedef unsigned int uintT;
using frag8 = __attribute__((ext_vector_type(8))) short;
using f32x4 = __attribute__((ext_vector_type(4))) float;

__device__ __forceinline__ float tanh_fast(float u) {
  float e = __expf(2.0f * u);
  return 1.0f - 2.0f / (e + 1.0f);
}
__device__ __forceinline__ float sigmoid_fast(float u) {
  return 1.0f / (1.0f + __expf(-u));
}
__device__ __forceinline__ ushortT f2bf(float f) {
  unsigned int u = __float_as_uint(f);
  unsigned int r = (u + 0x7FFFu + ((u >> 16) & 1u)) >> 16;
  return (ushortT)r;
}
__device__ __forceinline__ float bflo(uintT u) { return __uint_as_float(u << 16); }
__device__ __forceinline__ float bfhi(uintT u) { return __uint_as_float(u & 0xffff0000u); }

__device__ __forceinline__ void wait_ge(int* p, int tgt) {
  while (__hip_atomic_load(p, __ATOMIC_RELAXED, __HIP_MEMORY_SCOPE_AGENT) < tgt)
    __builtin_amdgcn_s_sleep(4);
}
__device__ __forceinline__ float aload(const float* p) {
  return __hip_atomic_load(p, __ATOMIC_RELAXED, __HIP_MEMORY_SCOPE_AGENT);
}
__device__ __forceinline__ void dot8(const float* cp, uint4 w, float& acc) {
  acc = fmaf(cp[0], bflo(w.x), acc); acc = fmaf(cp[1], bfhi(w.x), acc);
  acc = fmaf(cp[2], bflo(w.y), acc); acc = fmaf(cp[3], bfhi(w.y), acc);
  acc = fmaf(cp[4], bflo(w.z), acc); acc = fmaf(cp[5], bfhi(w.z), acc);
  acc = fmaf(cp[6], bflo(w.w), acc); acc = fmaf(cp[7], bfhi(w.w), acc);
}

// ---------- prep: bf16 conversions + WxT transpose ----------
__global__ __launch_bounds__(256) void conv_kernel(
    const float* __restrict__ Wx, const float* __restrict__ W_cls,
    const float* __restrict__ W_ih, const float* __restrict__ W_hh,
    const float* __restrict__ Wh,
    ushortT* __restrict__ Wcls_bf, ushortT* __restrict__ Wih_bf,
    ushortT* __restrict__ Whh_bf, ushortT* __restrict__ Wh_bf,
    ushortT* __restrict__ WxT_bf) {
  int blk = blockIdx.x;
  const int tid = threadIdx.x;
  if (blk < 384) {
    const float* src; ushortT* dst; int base, srcn;
    if (blk < 280)      { src = W_cls; dst = Wcls_bf; base = blk * 4096;        srcn = CC * 256; }
    else if (blk < 328) { src = W_ih;  dst = Wih_bf;  base = (blk - 280) * 4096; srcn = 768 * 256; }
    else if (blk < 376) { src = W_hh;  dst = Whh_bf;  base = (blk - 328) * 4096; srcn = 768 * 256; }
    else                { src = Wh;    dst = Wh_bf;   base = (blk - 376) * 4096; srcn = 256 * 128; }
#pragma unroll
    for (int i = 0; i < 16; ++i) {
      int idx = base + i * 256 + tid;
      dst[idx] = (idx < srcn) ? f2bf(src[idx]) : (ushortT)0;
    }
  } else {  // Wx [256][128] -> WxT_bf [128][256]
    blk -= 384;  // 0..31
    __shared__ float tile[32][33];
    const int li = tid >> 5, lj = tid & 31;
    int i0 = (blk >> 2) * 32, j0 = (blk & 3) * 32;
#pragma unroll
    for (int k = 0; k < 4; ++k)
      tile[li + k * 8][lj] = Wx[(size_t)(i0 + li + k * 8) * 128 + j0 + lj];
    __syncthreads();
#pragma unroll
    for (int k = 0; k < 4; ++k) {
      int j = j0 + li + k * 8;
      WxT_bf[(size_t)j * 256 + i0 + lj] = f2bf(tile[lj][li + k * 8]);
    }
  }
}

// ---------- xW via MFMA bf16 (validated round 4): emits x_bf and xWT ----------
__global__ __launch_bounds__(256) void xw_mfma(
    const float* __restrict__ x, const ushortT* __restrict__ WxT_bf,
    ushortT* __restrict__ x_bf, ushortT* __restrict__ xWT) {
  __shared__ ushortT lds[2 * 128 * 72];
#define SX(r, c) lds[(r) * 72 + (c)]
#define SW(r, c) lds[128 * 72 + (r) * 72 + (c)]
#define ST(a, m) lds[(a) * 136 + (m)]
  const int tid = threadIdx.x;
  const int lane = tid & 63, w = tid >> 6;
  const int l15 = lane & 15, quad = lane >> 4;
  const int r0 = blockIdx.x * 128;
  const int bb = blockIdx.x >> 4, t0 = (blockIdx.x & 15) * 128;
  const int row = tid >> 1, half = tid & 1;

  f32x4 acc[2][8];
#pragma unroll
  for (int mt = 0; mt < 2; ++mt)
#pragma unroll
    for (int nt = 0; nt < 8; ++nt) acc[mt][nt] = (f32x4){0.f, 0.f, 0.f, 0.f};

  for (int kk0 = 0; kk0 < 256; kk0 += 64) {
    {
      const float4* xp = (const float4*)(x + (size_t)(r0 + row) * DD + kk0 + half * 32);
      uint4 pk[4];
#pragma unroll
      for (int i = 0; i < 4; ++i) {
        float4 f0 = xp[2 * i], f1 = xp[2 * i + 1];
        pk[i].x = (uintT)f2bf(f0.x) | ((uintT)f2bf(f0.y) << 16);
        pk[i].y = (uintT)f2bf(f0.z) | ((uintT)f2bf(f0.w) << 16);
        pk[i].z = (uintT)f2bf(f1.x) | ((uintT)f2bf(f1.y) << 16);
        pk[i].w = (uintT)f2bf(f1.z) | ((uintT)f2bf(f1.w) << 16);
      }
      uint4* sxp = (uint4*)&SX(row, half * 32);
      uint4* gxp = (uint4*)(x_bf + (size_t)(r0 + row) * DD + kk0 + half * 32);
#pragma unroll
      for (int i = 0; i < 4; ++i) { sxp[i] = pk[i]; gxp[i] = pk[i]; }
    }
    {
      const uint4* wp = (const uint4*)(WxT_bf + (size_t)row * DD + kk0 + half * 32);
      uint4* swp = (uint4*)&SW(row, half * 32);
#pragma unroll
      for (int i = 0; i < 4; ++i) swp[i] = wp[i];
    }
    __syncthreads();
#pragma unroll
    for (int kk = 0; kk < 2; ++kk) {
      frag8 a0 = *(const frag8*)&SX(w * 32 + l15, kk * 32 + quad * 8);
      frag8 a1 = *(const frag8*)&SX(w * 32 + 16 + l15, kk * 32 + quad * 8);
#pragma unroll
      for (int nt = 0; nt < 8; ++nt) {
        frag8 bf = *(const frag8*)&SW(nt * 16 + l15, kk * 32 + quad * 8);
        acc[0][nt] = __builtin_amdgcn_mfma_f32_16x16x32_bf16(a0, bf, acc[0][nt], 0, 0, 0);
        acc[1][nt] = __builtin_amdgcn_mfma_f32_16x16x32_bf16(a1, bf, acc[1][nt], 0, 0, 0);
      }
    }
    __syncthreads();
  }
#pragma unroll
  for (int mt = 0; mt < 2; ++mt)
#pragma unroll
    for (int nt = 0; nt < 8; ++nt)
#pragma unroll
      for (int r = 0; r < 4; ++r) {
        int m = w * 32 + mt * 16 + quad * 4 + r;
        int a = nt * 16 + l15;
        ST(a, m) = f2bf(acc[mt][nt][r]);
      }
  __syncthreads();
  {
    const uint4* sp = (const uint4*)&ST(row, half * 64);
    uint4* gp = (uint4*)(xWT + ((size_t)bb * AA + row) * TT + t0 + half * 64);
#pragma unroll
    for (int i = 0; i < 8; ++i) gp[i] = sp[i];
  }
#undef SX
#undef SW
#undef ST
}

// ---------- persistent step kernel (PLAIN launch — no cooperative API) ----------
// Round-6 postmortem: bit-identical 0.247 absmax across two builds ==
// deterministic "out = b_cls" == step_coop never ran; hipLaunchCooperativeKernel's
// (ignored) error was the failure. We use no grid.sync, so cooperative launch was
// never needed. Grid 288 <= 512 co-resident (launch_bounds(256,2)) -> no deadlock.
// Blocks 0..255: attention (b = id>>3, 256-t chunk). Blocks 256..287: GRU (one per b).
__global__ __launch_bounds__(256, 2) void step_coop(
    const ushortT* __restrict__ x_bf, const ushortT* __restrict__ xWT,
    const ushortT* __restrict__ Wih_bf, const ushortT* __restrict__ Whh_bf,
    const ushortT* __restrict__ Wh_bf, const float* __restrict__ v,
    const float* __restrict__ b_ih, const float* __restrict__ b_hh,
    float* ctx_acc, float* den, float* hwh_s, ushortT* hall_bf,
    int* ctxcnt, int* hcnt) {
  __shared__ float smem[2592];
  const int tid = threadIdx.x;
  const int id = blockIdx.x;
  if (id < 256) {
    // ================= attention role =================
    // smem: [0,128) hWh | [128,256) v | [256,1280) parts | [1280,1536) w | [1536,2560) cpart
    const int b = id >> 3, t0 = (id & 7) * 256;
    if (tid < 128) smem[128 + tid] = v[tid];
    for (int s = 0; s < NSTEPS; ++s) {
      if (s > 0) {
        if (tid == 0) wait_ge(&hcnt[s * 32 + b], 1);
        __syncthreads();
        __builtin_amdgcn_fence(__ATOMIC_ACQUIRE, "agent");
        if (tid < 128) smem[tid] = aload(&hwh_s[(size_t)(s * 32 + b) * 128 + tid]);
      } else {
        if (tid < 128) smem[tid] = 0.f;
      }
      __syncthreads();
      // Phase A: scores for 256 t's. wave q covers a in [q*32, q*32+32)
      {
        const int q = tid >> 6, tp = tid & 63;
        const ushortT* base0 = xWT + (size_t)(b * AA + q * 32) * TT + t0;
#pragma unroll
        for (int th = 0; th < 2; ++th) {
          const int tt = th * 128 + 2 * tp;
          float p0 = 0.f, p1 = 0.f;
#pragma unroll 8
          for (int i = 0; i < 32; ++i) {
            uintT u = *(const uintT*)(base0 + (size_t)i * TT + tt);
            int a = q * 32 + i;
            float hwa = smem[a], va = smem[128 + a];
            p0 = fmaf(tanh_fast(bflo(u) + hwa), va, p0);
            p1 = fmaf(tanh_fast(bfhi(u) + hwa), va, p1);
          }
          smem[256 + q * 256 + tt] = p0;
          smem[256 + q * 256 + tt + 1] = p1;
        }
      }
      __syncthreads();
      {
        float e = smem[256 + tid] + smem[512 + tid] + smem[768 + tid] + smem[1024 + tid];
        smem[1280 + tid] = __expf(e);  // |e| <= ||v||_1 ~ 5: no overflow
      }
      __syncthreads();
      // Phase B: ctx partials over 256 t's
      {
        const int j4 = tid >> 6, dq = tid & 63;
        float ax = 0.f, ay = 0.f, az = 0.f, aw = 0.f;
        const uint2* xb = (const uint2*)(x_bf + ((size_t)b * TT + t0) * DD);
#pragma unroll 8
        for (int j = 0; j < 64; ++j) {
          int tl = j * 4 + j4;
          float w = smem[1280 + tl];
          uint2 u = xb[(size_t)tl * 64 + dq];
          ax = fmaf(w, bflo(u.x), ax); ay = fmaf(w, bfhi(u.x), ay);
          az = fmaf(w, bflo(u.y), az); aw = fmaf(w, bfhi(u.y), aw);
        }
        float4* pp = (float4*)&smem[1536 + j4 * 256 + dq * 4];
        *pp = make_float4(ax, ay, az, aw);
      }
      __syncthreads();
      {
        float sum = smem[1536 + tid] + smem[1792 + tid] + smem[2048 + tid] + smem[2304 + tid];
        atomicAdd(&ctx_acc[((size_t)s * 32 + b) * DD + tid], sum);
      }
      if (tid < 64) {
        float ds = smem[1280 + tid] + smem[1344 + tid] + smem[1408 + tid] + smem[1472 + tid];
#pragma unroll
        for (int off = 32; off > 0; off >>= 1) ds += __shfl_down(ds, off, 64);
        if (tid == 0) atomicAdd(&den[s * 32 + b], ds);
      }
      __syncthreads();  // drains vmcnt -> block's atomics globally visible
      if (tid == 0) {
        __builtin_amdgcn_fence(__ATOMIC_RELEASE, "agent");
        __hip_atomic_fetch_add(&ctxcnt[s * 32 + b], 1, __ATOMIC_RELAXED, __HIP_MEMORY_SCOPE_AGENT);
      }
    }
  } else {
    // ================= GRU role (one block per b) =================
    const int b = id - 256;
    smem[272 + tid + (tid >> 4)] = 0.f;  // h0 = 0 (stride-17 padded)
    for (int s = 1; s <= NSTEPS; ++s) {
      if (tid == 0) wait_ge(&ctxcnt[(s - 1) * 32 + b], 8);
      __syncthreads();
      __builtin_amdgcn_fence(__ATOMIC_ACQUIRE, "agent");
      float dv = aload(&den[(s - 1) * 32 + b]);
      float invd = 1.0f / dv;
      smem[tid + (tid >> 4)] =
          aload(&ctx_acc[((size_t)(s - 1) * 32 + b) * DD + tid]) * invd;
      __syncthreads();
      // gates: 16 lanes per gate, stride-17 LDS (conflict-free), bf16 weights
      {
        const int g16 = tid >> 4, l16 = tid & 15;
        const float* cp = &smem[l16 * 17];
        const float* hp = &smem[272 + l16 * 17];
        for (int p = 0; p < 48; ++p) {
          int g = p * 16 + g16;
          const uint4* wi = (const uint4*)(Wih_bf + (size_t)g * DD + l16 * 16);
          const uint4* wh = (const uint4*)(Whh_bf + (size_t)g * HH + l16 * 16);
          uint4 wa = wi[0], wb = wi[1], wc = wh[0], wd = wh[1];
          float gi = 0.f, gh = 0.f;
          dot8(cp, wa, gi); dot8(cp + 8, wb, gi);
          dot8(hp, wc, gh); dot8(hp + 8, wd, gh);
#pragma unroll
          for (int off = 8; off > 0; off >>= 1) {
            gi += __shfl_down(gi, off, 16);
            gh += __shfl_down(gh, off, 16);
          }
          if (l16 == 0) { smem[544 + g] = gi; smem[1312 + g] = gh; }
        }
      }
      __syncthreads();
      {
        int i = tid;
        float gir = smem[544 + i] + b_ih[i];
        float giz = smem[800 + i] + b_ih[256 + i];
        float gin = smem[1056 + i] + b_ih[512 + i];
        float ghr = smem[1312 + i] + b_hh[i];
        float ghz = smem[1568 + i] + b_hh[256 + i];
        float ghn = smem[1824 + i] + b_hh[512 + i];
        float r = sigmoid_fast(gir + ghr);
        float z = sigmoid_fast(giz + ghz);
        float n = tanh_fast(gin + r * ghn);
        float hv = (1.f - z) * n + z * smem[272 + i + (i >> 4)];
        smem[272 + i + (i >> 4)] = hv;  // own slot: read then write, no race
        hall_bf[((size_t)(s - 1) * 32 + b) * HH + i] = f2bf(hv);
      }
      __syncthreads();
      if (s < NSTEPS) {
        // hWh: thread (a-pair, k-quarter)
        const int a2 = tid & 63, kh = tid >> 6;
        float accx = 0.f, accy = 0.f;
#pragma unroll 8
        for (int k = kh * 64; k < kh * 64 + 64; ++k) {
          uintT u = *(const uintT*)(Wh_bf + (size_t)k * AA + a2 * 2);
          float hh = smem[272 + k + (k >> 4)];
          accx = fmaf(hh, bflo(u), accx);
          accy = fmaf(hh, bfhi(u), accy);
        }
        smem[2080 + kh * 128 + a2 * 2] = accx;
        smem[2080 + kh * 128 + a2 * 2 + 1] = accy;
        __syncthreads();
        if (tid < 128) {
          float hw = smem[2080 + tid] + smem[2208 + tid] + smem[2336 + tid] + smem[2464 + tid];
          __hip_atomic_store(&hwh_s[(size_t)(s * 32 + b) * 128 + tid], hw,
                             __ATOMIC_RELAXED, __HIP_MEMORY_SCOPE_AGENT);
        }
        __syncthreads();
        if (tid == 0) {
          __builtin_amdgcn_fence(__ATOMIC_RELEASE, "agent");
          __hip_atomic_fetch_add(&hcnt[s * 32 + b], 1, __ATOMIC_RELAXED,
                                 __HIP_MEMORY_SCOPE_AGENT);
        }
      }
    }
  }
}

// ---------- cls via MFMA bf16: [704 x 256] @ [256 x 4480] ----------
__global__ __launch_bounds__(256) void cls_mfma(
    const ushortT* __restrict__ hall_bf, const ushortT* __restrict__ Wcls_bf,
    const float* __restrict__ b_cls, float* __restrict__ out) {
  __shared__ ushortT sA[64 * 264];
  const int tid = threadIdx.x;
  const int n0 = blockIdx.x * 128, m0 = blockIdx.y * 64;
  {
    const int r = tid >> 2, seg = tid & 3;
    const uint4* src = (const uint4*)hall_bf;
    uint4* dstrow = (uint4*)(sA + r * 264);
#pragma unroll
    for (int j = 0; j < 8; ++j)
      dstrow[seg * 8 + j] = src[(size_t)(m0 + r) * 32 + seg * 8 + j];
  }
  __syncthreads();
  const int lane = tid & 63, w = tid >> 6;
  const int l15 = lane & 15, quad = lane >> 4;
  f32x4 acc[8];
#pragma unroll
  for (int nt = 0; nt < 8; ++nt) acc[nt] = (f32x4){0.f, 0.f, 0.f, 0.f};
#pragma unroll
  for (int kk = 0; kk < 8; ++kk) {
    frag8 af = *(const frag8*)(sA + (w * 16 + l15) * 264 + kk * 32 + quad * 8);
#pragma unroll
    for (int nt = 0; nt < 8; ++nt) {
      frag8 bf = *(const frag8*)(Wcls_bf + (size_t)(n0 + nt * 16 + l15) * 256 + kk * 32 + quad * 8);
      acc[nt] = __builtin_amdgcn_mfma_f32_16x16x32_bf16(af, bf, acc[nt], 0, 0, 0);
    }
  }
#pragma unroll
  for (int nt = 0; nt < 8; ++nt) {
    int n = n0 + nt * 16 + l15;
    if (n < CC) {
      float bc = b_cls[n];
#pragma unroll
      for (int r = 0; r < 4; ++r) {
        int m = m0 + w * 16 + quad * 4 + r;  // m = s*32 + b
        int st = m >> 5, bb = m & 31;
        out[((size_t)bb * NSTEPS + st) * CC + n] = acc[nt][r] + bc;
      }
    }
  }
}

extern "C" void kernel_launch(void* const* d_in, const int* in_sizes, int n_in,
                              void* d_out, int out_size, void* d_ws, size_t ws_size,
                              hipStream_t stream) {
  const float* x     = (const float*)d_in[0];
  const float* Wx    = (const float*)d_in[1];
  const float* Wh    = (const float*)d_in[2];
  const float* v     = (const float*)d_in[3];
  const float* W_ih  = (const float*)d_in[4];
  const float* W_hh  = (const float*)d_in[5];
  const float* b_ih  = (const float*)d_in[6];
  const float* b_hh  = (const float*)d_in[7];
  const float* W_cls = (const float*)d_in[8];
  const float* b_cls = (const float*)d_in[9];
  float* out = (float*)d_out;

  // workspace layout (~52.5 MiB)
  float* ctx_acc = (float*)d_ws;                       // 22*32*256 = 180224
  float* den     = ctx_acc + (size_t)NSTEPS * BB * DD; // 704
  int*   ctxcnt  = (int*)(den + NSTEPS * BB);          // 704
  int*   hcnt    = ctxcnt + NSTEPS * BB;               // 736
  float* hwh_s   = (float*)(hcnt + 736);               // 23*32*128 = 94208
  ushortT* hall_bf = (ushortT*)(hwh_s + 94208);        // 704*256 = 180224
  ushortT* Wih_bf  = hall_bf + 180224;                 // 768*256
  ushortT* Whh_bf  = Wih_bf + 196608;                  // 768*256
  ushortT* Wh_bf   = Whh_bf + 196608;                  // 256*128
  ushortT* Wcls_bf = Wh_bf + 32768;                    // 4480*256
  ushortT* WxT_bf  = Wcls_bf + 1146880;                // 128*256
  ushortT* x_bf    = WxT_bf + 32768;                   // 65536*256
  ushortT* xWT     = x_bf + (size_t)BB * TT * DD;      // 32*128*2048

  hipMemsetAsync(ctx_acc, 0,
                 (size_t)(NSTEPS * BB * DD + NSTEPS * BB + NSTEPS * BB + 736) * sizeof(float),
                 stream);
  conv_kernel<<<416, 256, 0, stream>>>(Wx, W_cls, W_ih, W_hh, Wh,
                                       Wcls_bf, Wih_bf, Whh_bf, Wh_bf, WxT_bf);
  xw_mfma<<<(BB * TT) / 128, 256, 0, stream>>>(x, WxT_bf, x_bf, xWT);

  step_coop<<<288, 256, 0, stream>>>(x_bf, xWT, Wih_bf, Whh_bf, Wh_bf, v,
                                     b_ih, b_hh, ctx_acc, den, hwh_s, hall_bf,
                                     ctxcnt, hcnt);

  cls_mfma<<<dim3(35, 11), 256, 0, stream>>>(hall_bf, Wcls_bf, b_cls, out);
}